// Round 4
// baseline (376.873 us; speedup 1.0000x reference)
//
#include <hip/hip_runtime.h>
#include <math.h>

#define EPS_F 1e-5f
#define NPOINTS 550   // sum_{i=1..10} 10*i
#define CIN 512
#define NITER 8       // 8 rows per stage, 64 rows per wave

// jax.nn.softplus(z) = max(z,0) + log1p(exp(-|z|))
static __device__ __forceinline__ float softplus_f(float z) {
    return fmaxf(z, 0.0f) + log1pf(expf(-fabsf(z)));
}

static __device__ __forceinline__ float dot8(const float4 a0, const float4 a1,
                                             const float4 w0, const float4 w1) {
    float s = a0.x * w0.x;
    s = fmaf(a0.y, w0.y, s);
    s = fmaf(a0.z, w0.z, s);
    s = fmaf(a0.w, w0.w, s);
    s = fmaf(a1.x, w1.x, s);
    s = fmaf(a1.y, w1.y, s);
    s = fmaf(a1.z, w1.z, s);
    s = fmaf(a1.w, w1.w, s);
    return s;
}

// Persistent-style: grid 512 x 256thr = 2048 waves, 64 rows/wave.
// Double-buffered loads, NO per-iteration barriers -> loads stay in flight.
__global__ __launch_bounds__(256, 2) void beta_unimodal_kernel(
    const float* __restrict__ x,
    const float* __restrict__ Wa, const float* __restrict__ ba,
    const float* __restrict__ Wb, const float* __restrict__ bb,
    float* __restrict__ out)
{
    __shared__ __align__(16) float2 tab[NPOINTS];   // (log2 g, log2(1-g))
    __shared__ float part[4][2][9][68];             // [wave][a/b][row(+pad)][lane(+pad)]

    const int tid = threadIdx.x;
    const int lane = tid & 63;
    const int wave = tid >> 6;
    const long waveRow0 = ((long)blockIdx.x * 4 + wave) * 64;

    // W in registers: lane l owns cols [4l..4l+3] and [256+4l..4l+3]
    const float4* Wa4 = (const float4*)Wa;
    const float4* Wb4 = (const float4*)Wb;
    const float4 wa0 = Wa4[lane], wa1 = Wa4[64 + lane];
    const float4 wb0 = Wb4[lane], wb1 = Wb4[64 + lane];

    // Stage-0 prefetch (independent of tab)
    float4 xs[2][8][2];
    #pragma unroll
    for (int r = 0; r < 8; ++r) {
        const float4* xr = (const float4*)(x + (waveRow0 + r) * CIN);
        xs[0][r][0] = xr[lane];
        xs[0][r][1] = xr[64 + lane];
    }

    for (int p = tid; p < NPOINTS; p += 256) {
        int i = 1, off = 0;
        while (p >= off + 10 * i) { off += 10 * i; ++i; }
        const int j = p - off;
        const int n = 10 * i;
        const float thr = (float)i * 0.1f;
        const float step = (thr - 2.0f * EPS_F) / (float)(n - 1);
        const float g = EPS_F + step * (float)j;          // matches jnp.linspace f32
        float2 e;
        e.x = log2f(g);
        e.y = log2f(1.0f - g);
        tab[p] = e;
    }
    __syncthreads();

    const float biasA = ba[0], biasB = bb[0];
    const int row = lane >> 3;           // 0..7 local row within the 8-row stage
    const int o = lane & 7;              // octet lane within the row
    const int v = o >> 2;                // 0 = alpha-sum, 1 = beta-sum
    const int qa = o & 3;                // quarter of the 64 partials

    #pragma unroll
    for (int t = 0; t < NITER; ++t) {
        const int cur = t & 1;

        // Prefetch next stage BEFORE consuming current (16 loads in flight)
        if (t + 1 < NITER) {
            #pragma unroll
            for (int r = 0; r < 8; ++r) {
                const float4* xr =
                    (const float4*)(x + (waveRow0 + (long)(t + 1) * 8 + r) * CIN);
                xs[cur ^ 1][r][0] = xr[lane];
                xs[cur ^ 1][r][1] = xr[64 + lane];
            }
        }

        // ---- Consume current stage: pure FMA partials ----
        float pa[8], pb[8];
        #pragma unroll
        for (int r = 0; r < 8; ++r) {
            pa[r] = dot8(xs[cur][r][0], xs[cur][r][1], wa0, wa1);
            pb[r] = dot8(xs[cur][r][0], xs[cur][r][1], wb0, wb1);
        }

        // ---- Per-wave LDS transpose reduction (wave-synchronous, in-order) ----
        #pragma unroll
        for (int r = 0; r < 8; ++r) {
            part[wave][0][r][lane] = pa[r];
            part[wave][1][r][lane] = pb[r];
        }
        asm volatile("s_waitcnt lgkmcnt(0)" ::: "memory");

        const float4* src4 = (const float4*)&part[wave][v][row][qa * 16];
        float s = 0.0f;
        #pragma unroll
        for (int c = 0; c < 4; ++c) {
            const float4 tt = src4[c];
            s += (tt.x + tt.y) + (tt.z + tt.w);
        }
        s += __shfl_xor(s, 1, 64);
        s += __shfl_xor(s, 2, 64);
        const float other = __shfl_xor(s, 4, 64);
        const float my_da = (v == 0) ? s : other;
        const float my_db = (v == 0) ? other : s;

        // ---- Phase 2: 8 lanes per row, pair-wise (float4 = 2 grid points) ----
        const float za = my_da + biasA;
        const float zb = my_db + biasB;
        const float alpha = fminf(fmaxf(1.0f + softplus_f(za), 1.0f), 100.0f);
        const float beta  = fminf(fmaxf(1.0f + softplus_f(zb), 1.0f), 100.0f);
        const float am1 = alpha - 1.0f;
        const float bm1 = beta - 1.0f;

        // Stabilizer at the Beta mode (lbeta/dx are common positive factors,
        // they cancel in the normalization; concavity => exp2 args <= 0).
        const float denom = am1 + bm1;
        float mode = (denom > 0.0f) ? (am1 / denom) : 0.5f;
        mode = fminf(fmaxf(mode, 1e-7f), 1.0f - 1.1920929e-7f);
        const float M2 = am1 * log2f(mode) + bm1 * log2f(1.0f - mode);

        float seg[10];
        int p0 = 0;
        #pragma unroll
        for (int i = 1; i <= 10; ++i) {
            const int n = 10 * i;           // even; p0 even -> float4 aligned
            float s2 = 0.0f;
            for (int j2 = 2 * o; j2 < n; j2 += 16) {
                const float4 tq = *(const float4*)&tab[p0 + j2];
                const float e0 = fmaf(am1, tq.x, bm1 * tq.y) - M2;
                const float e1 = fmaf(am1, tq.z, bm1 * tq.w) - M2;
                s2 += __builtin_amdgcn_exp2f(e0) + __builtin_amdgcn_exp2f(e1);
            }
            s2 += __shfl_xor(s2, 1, 64);
            s2 += __shfl_xor(s2, 2, 64);
            s2 += __shfl_xor(s2, 4, 64);    // all 8 row-lanes hold full sum
            seg[i - 1] = s2;
            p0 += n;
        }

        // ---- Epilogue: static seg[] indexing, direct coalesced-ish stores ----
        const float inv = 1.0f / seg[9];
        float v0 = 0.0f, v1 = 0.0f;
        #pragma unroll
        for (int k = 0; k < 10; ++k) {
            const float pv = (seg[k] - (k ? seg[k - 1] : 0.0f)) * inv;
            if (k < 8) { if (o == k) v0 = pv; }
            else       { if (o == k - 8) v1 = pv; }
        }
        float* orow = out + (waveRow0 + (long)t * 8 + row) * 10;
        orow[o] = v0;                       // rows 0..7 x elems 0..7 (one instr)
        if (o < 2) orow[8 + o] = v1;        // elems 8,9
    }
}

extern "C" void kernel_launch(void* const* d_in, const int* in_sizes, int n_in,
                              void* d_out, int out_size, void* d_ws, size_t ws_size,
                              hipStream_t stream) {
    const float* x  = (const float*)d_in[0];
    const float* Wa = (const float*)d_in[1];
    const float* ba = (const float*)d_in[2];
    const float* Wb = (const float*)d_in[3];
    const float* bb = (const float*)d_in[4];
    float* out = (float*)d_out;

    const int batch = in_sizes[0] / CIN;         // 131072
    const int blocks = batch / (4 * 64);         // 512 blocks = 2/CU, persistent
    beta_unimodal_kernel<<<blocks, 256, 0, stream>>>(x, Wa, ba, Wb, bb, out);
}